// Round 1
// baseline (501.928 us; speedup 1.0000x reference)
//
#include <hip/hip_runtime.h>
#include <hip/hip_bf16.h>

// Problem constants: B=2, S=2048, DIM=2048, H=16, KVH=8, D=128
// qkv packed columns: [0,2048)=Q (h*128+d), [2048,3072)=K, [3072,4096)=V

typedef __attribute__((ext_vector_type(8))) short s16x8;   // 8 bf16 in 4 VGPRs
typedef __attribute__((ext_vector_type(4))) float f32x4;

static __device__ __forceinline__ unsigned short f2bf(float f) {
    union { float f; unsigned u; } v; v.f = f;
    unsigned r = v.u + 0x7FFF + ((v.u >> 16) & 1);   // RNE
    return (unsigned short)(r >> 16);
}
static __device__ __forceinline__ float bf2f(unsigned short h) {
    union { unsigned u; float f; } v; v.u = ((unsigned)h) << 16;
    return v.f;
}

// ---------------- f32 -> bf16 elementwise convert (x) ----------------
__global__ __launch_bounds__(256) void k_convert_x(const float* __restrict__ x,
                                                   unsigned short* __restrict__ xb, int n) {
    int i = (blockIdx.x * 256 + threadIdx.x) * 8;
    if (i >= n) return;
    float4 a = *(const float4*)(x + i);
    float4 b = *(const float4*)(x + i + 4);
    s16x8 o;
    o[0] = (short)f2bf(a.x); o[1] = (short)f2bf(a.y); o[2] = (short)f2bf(a.z); o[3] = (short)f2bf(a.w);
    o[4] = (short)f2bf(b.x); o[5] = (short)f2bf(b.y); o[6] = (short)f2bf(b.z); o[7] = (short)f2bf(b.w);
    *(s16x8*)(xb + i) = o;
}

// ---------------- weight transpose f32 (K x N) -> bf16 (N x K) ----------------
__global__ __launch_bounds__(256) void k_transpose_w(const float* __restrict__ src,
                                                     unsigned short* __restrict__ dst,
                                                     int K, int N, int nbase, int dstld) {
    __shared__ float t[32][33];
    int k0 = blockIdx.x * 32, n0 = blockIdx.y * 32;
    int tx = threadIdx.x & 31, ty0 = threadIdx.x >> 5;
    for (int p = 0; p < 4; p++) {
        int ty = ty0 + p * 8;
        t[ty][tx] = src[(size_t)(k0 + ty) * N + n0 + tx];
    }
    __syncthreads();
    for (int p = 0; p < 4; p++) {
        int ty = ty0 + p * 8;
        dst[(size_t)(nbase + n0 + ty) * dstld + k0 + tx] = f2bf(t[tx][ty]);
    }
}

// ---------------- GEMM: C(MxN) = A(MxK) * Bt(NxK)^T, bf16 in, f32 acc ----------------
// 128x128 tile, 4 waves (2x2), BK=32, LDS padded stride 40 (conflict-free reads)
template<int OUTF32>
__global__ __launch_bounds__(256) void k_gemm_bt(const unsigned short* __restrict__ A,
                                                 const unsigned short* __restrict__ Bt,
                                                 void* __restrict__ Cout,
                                                 int M, int N, int K) {
    __shared__ unsigned short As[128][40];
    __shared__ unsigned short Bs[128][40];
    int tid = threadIdx.x;
    int lane = tid & 63;
    int wave = tid >> 6;
    int wm = wave >> 1, wn = wave & 1;
    int lr = lane & 15, lk = (lane >> 4) * 8;
    int sr = tid >> 1, sc = (tid & 1) * 16;
    const unsigned short* Arow = A + (size_t)(blockIdx.x * 128 + sr) * K + sc;
    const unsigned short* Brow = Bt + (size_t)(blockIdx.y * 128 + sr) * K + sc;
    f32x4 acc[4][4] = {};
    for (int k0 = 0; k0 < K; k0 += 32) {
        __syncthreads();
        *(s16x8*)&As[sr][sc]     = *(const s16x8*)(Arow + k0);
        *(s16x8*)&As[sr][sc + 8] = *(const s16x8*)(Arow + k0 + 8);
        *(s16x8*)&Bs[sr][sc]     = *(const s16x8*)(Brow + k0);
        *(s16x8*)&Bs[sr][sc + 8] = *(const s16x8*)(Brow + k0 + 8);
        __syncthreads();
        s16x8 af[4], bfr[4];
        for (int m = 0; m < 4; m++) af[m]  = *(const s16x8*)&As[wm * 64 + m * 16 + lr][lk];
        for (int n = 0; n < 4; n++) bfr[n] = *(const s16x8*)&Bs[wn * 64 + n * 16 + lr][lk];
        for (int m = 0; m < 4; m++)
            for (int n = 0; n < 4; n++)
                acc[m][n] = __builtin_amdgcn_mfma_f32_16x16x32_bf16(af[m], bfr[n], acc[m][n], 0, 0, 0);
    }
    int rbase = blockIdx.x * 128 + wm * 64;
    int cbase = blockIdx.y * 128 + wn * 64;
    for (int m = 0; m < 4; m++)
        for (int n = 0; n < 4; n++)
            for (int r = 0; r < 4; r++) {
                int row = rbase + m * 16 + (lane >> 4) * 4 + r;
                int col = cbase + n * 16 + lr;
                float v = acc[m][n][r];
                if (OUTF32) ((float*)Cout)[(size_t)row * N + col] = v;
                else        ((unsigned short*)Cout)[(size_t)row * N + col] = f2bf(v);
            }
}

// ---------------- fused RMSNorm + RoPE + head transpose ----------------
// one block per (b,s) row; wave w handles segments w, w+4, ... of 32 x 128-wide heads
__global__ __launch_bounds__(256) void k_rms_rope(const unsigned short* __restrict__ qkv,
                                                  const float* __restrict__ qg,
                                                  const float* __restrict__ kg,
                                                  const float* __restrict__ cosc,
                                                  const float* __restrict__ sinc,
                                                  unsigned short* __restrict__ Qt,
                                                  unsigned short* __restrict__ Kt,
                                                  unsigned short* __restrict__ Vt) {
    int r = blockIdx.x;            // b*2048 + s
    int b = r >> 11;
    int s = r & 2047;
    int wave = threadIdx.x >> 6, lane = threadIdx.x & 63;
    const unsigned short* row = qkv + (size_t)r * 4096;
    float c  = cosc[s * 64 + lane];
    float sn = sinc[s * 64 + lane];
    for (int seg = wave; seg < 32; seg += 4) {
        int col0 = seg * 128;
        float e0 = bf2f(row[col0 + lane]);
        float e1 = bf2f(row[col0 + 64 + lane]);
        if (seg < 24) {
            float ss = e0 * e0 + e1 * e1;
            for (int m = 1; m < 64; m <<= 1) ss += __shfl_xor(ss, m, 64);
            float rn = rsqrtf(ss * (1.0f / 128.0f) + 1e-6f);
            const float* g = (seg < 16) ? qg : kg;
            float t0 = e0 * rn * g[lane];
            float t1 = e1 * rn * g[lane + 64];
            float o0 = t0 * c - t1 * sn;
            float o1 = t1 * c + t0 * sn;
            unsigned short* dst;
            if (seg < 16) dst = Qt + ((size_t)(b * 16 + seg) * 2048 + s) * 128;
            else          dst = Kt + ((size_t)(b * 8 + (seg - 16)) * 2048 + s) * 128;
            dst[lane]      = f2bf(o0);
            dst[lane + 64] = f2bf(o1);
        } else {
            unsigned short* dst = Vt + ((size_t)(b * 8 + (seg - 24)) * 2048 + s) * 128;
            dst[lane]      = row[col0 + lane];
            dst[lane + 64] = row[col0 + 64 + lane];
        }
    }
}

// ---------------- causal GQA flash attention ----------------
// 1 wave per 16 q-rows; KV tile = 32; online softmax; P through LDS
__global__ __launch_bounds__(64) void k_attn(const unsigned short* __restrict__ Qt,
                                             const unsigned short* __restrict__ Kt,
                                             const unsigned short* __restrict__ Vt,
                                             unsigned short* __restrict__ attn) {
    __shared__ unsigned short Plds[16][32];
    int q0 = blockIdx.x * 16;
    int bh = blockIdx.y;           // b*16 + h
    int b = bh >> 4, h = bh & 15;
    int kvh = h >> 1;
    int lane = threadIdx.x;
    int lr = lane & 15, lg = lane >> 4;
    const unsigned short* Qbase = Qt + ((size_t)bh * 2048 + q0) * 128;
    const unsigned short* Kbase = Kt + (size_t)(b * 8 + kvh) * 2048 * 128;
    const unsigned short* Vbase = Vt + (size_t)(b * 8 + kvh) * 2048 * 128;
    s16x8 aq[4];
    for (int f = 0; f < 4; f++)
        aq[f] = *(const s16x8*)(Qbase + (size_t)lr * 128 + f * 32 + lg * 8);
    f32x4 out[8] = {};
    float mrow[4] = {-1e30f, -1e30f, -1e30f, -1e30f};
    float lrow[4] = {0.f, 0.f, 0.f, 0.f};
    const float scale = 0.08838834764831845f;  // 1/sqrt(128)
    int ntiles = (q0 + 15) / 32 + 1;
    for (int t = 0; t < ntiles; t++) {
        int k0 = t * 32;
        f32x4 sA = {0.f, 0.f, 0.f, 0.f}, sB = {0.f, 0.f, 0.f, 0.f};
        for (int f = 0; f < 4; f++) {
            s16x8 bkA = *(const s16x8*)(Kbase + (size_t)(k0 + lr) * 128 + f * 32 + lg * 8);
            s16x8 bkB = *(const s16x8*)(Kbase + (size_t)(k0 + 16 + lr) * 128 + f * 32 + lg * 8);
            sA = __builtin_amdgcn_mfma_f32_16x16x32_bf16(aq[f], bkA, sA, 0, 0, 0);
            sB = __builtin_amdgcn_mfma_f32_16x16x32_bf16(aq[f], bkB, sB, 0, 0, 0);
        }
        float pA[4], pB[4], sc[4];
        for (int r = 0; r < 4; r++) {
            int qglob = q0 + lg * 4 + r;
            float a  = (k0 + lr      <= qglob) ? sA[r] * scale : -1e30f;
            float b2 = (k0 + 16 + lr <= qglob) ? sB[r] * scale : -1e30f;
            float mx = fmaxf(a, b2);
            for (int mk = 1; mk < 16; mk <<= 1) mx = fmaxf(mx, __shfl_xor(mx, mk, 16));
            float mnew = fmaxf(mrow[r], mx);
            float sf = __expf(mrow[r] - mnew);
            mrow[r] = mnew;
            float ea = __expf(a - mnew);
            float eb = __expf(b2 - mnew);
            float rs = ea + eb;
            for (int mk = 1; mk < 16; mk <<= 1) rs += __shfl_xor(rs, mk, 16);
            lrow[r] = lrow[r] * sf + rs;
            pA[r] = ea; pB[r] = eb; sc[r] = sf;
        }
        for (int blk = 0; blk < 8; blk++)
            for (int r = 0; r < 4; r++) out[blk][r] *= sc[r];
        __syncthreads();
        for (int r = 0; r < 4; r++) {
            Plds[lg * 4 + r][lr]      = f2bf(pA[r]);
            Plds[lg * 4 + r][lr + 16] = f2bf(pB[r]);
        }
        __syncthreads();
        s16x8 ap = *(const s16x8*)&Plds[lr][lg * 8];
        for (int blk = 0; blk < 8; blk++) {
            s16x8 bv;
            for (int i = 0; i < 8; i++)
                bv[i] = (short)Vbase[(size_t)(k0 + lg * 8 + i) * 128 + blk * 16 + lr];
            out[blk] = __builtin_amdgcn_mfma_f32_16x16x32_bf16(ap, bv, out[blk], 0, 0, 0);
        }
    }
    float inv[4];
    for (int r = 0; r < 4; r++) inv[r] = 1.0f / lrow[r];
    for (int blk = 0; blk < 8; blk++)
        for (int r = 0; r < 4; r++) {
            int row = q0 + lg * 4 + r;
            attn[((size_t)(b * 2048) + row) * 2048 + h * 128 + blk * 16 + lr] =
                f2bf(out[blk][r] * inv[r]);
        }
}

extern "C" void kernel_launch(void* const* d_in, const int* in_sizes, int n_in,
                              void* d_out, int out_size, void* d_ws, size_t ws_size,
                              hipStream_t stream) {
    const float* x    = (const float*)d_in[0];
    const float* wq   = (const float*)d_in[1];
    const float* wk   = (const float*)d_in[2];
    const float* wv   = (const float*)d_in[3];
    const float* wo   = (const float*)d_in[4];
    const float* qg   = (const float*)d_in[5];
    const float* kg   = (const float*)d_in[6];
    const float* cosc = (const float*)d_in[7];
    const float* sinc = (const float*)d_in[8];

    char* ws = (char*)d_ws;
    // workspace layout (bytes); total = 120 MiB
    unsigned short* xb   = (unsigned short*)(ws);                 // 16 MiB  x bf16 (4096x2048)
    unsigned short* w1t  = (unsigned short*)(ws + 16777216);      // 16 MiB  packed [wq|wk|wv]^T (4096x2048)
    unsigned short* w2t  = (unsigned short*)(ws + 33554432);      //  8 MiB  wo^T (2048x2048)
    unsigned short* qkv  = (unsigned short*)(ws + 41943040);      // 32 MiB  (4096x4096)
    unsigned short* Qt   = (unsigned short*)(ws + 75497472);      // 16 MiB  (2,16,2048,128)
    unsigned short* Kt   = (unsigned short*)(ws + 92274688);      //  8 MiB  (2,8,2048,128)
    unsigned short* Vt   = (unsigned short*)(ws + 100663296);     //  8 MiB  (2,8,2048,128)
    unsigned short* attn = (unsigned short*)(ws + 109051904);     // 16 MiB  (4096x2048)

    k_convert_x<<<4096, 256, 0, stream>>>(x, xb, 8388608);
    k_transpose_w<<<dim3(64, 64), 256, 0, stream>>>(wq, w1t, 2048, 2048, 0, 2048);
    k_transpose_w<<<dim3(64, 32), 256, 0, stream>>>(wk, w1t, 2048, 1024, 2048, 2048);
    k_transpose_w<<<dim3(64, 32), 256, 0, stream>>>(wv, w1t, 2048, 1024, 3072, 2048);
    k_transpose_w<<<dim3(64, 64), 256, 0, stream>>>(wo, w2t, 2048, 2048, 0, 2048);
    k_gemm_bt<0><<<dim3(32, 32), 256, 0, stream>>>(xb, w1t, qkv, 4096, 4096, 2048);
    k_rms_rope<<<4096, 256, 0, stream>>>(qkv, qg, kg, cosc, sinc, Qt, Kt, Vt);
    k_attn<<<dim3(128, 32), 64, 0, stream>>>(Qt, Kt, Vt, attn);
    k_gemm_bt<1><<<dim3(32, 16), 256, 0, stream>>>(attn, w2t, d_out, 4096, 2048, 2048);
}